// Round 6
// baseline (6133.981 us; speedup 1.0000x reference)
//
#include <hip/hip_runtime.h>
#include <stdint.h>
#include <stddef.h>

// Problem dims (fixed): B=32 TENC=2048 LIS=512 HID=512 EMB=256 CLS=64 KEY=128 VAL=128 T=64 steps
// Outputs (f32, concat): logits [64,32,64] @0 ; preds.T [32,64] @131072 ; atts [64,32,2048] @133120
// Structure: k_init + k_proj + k_tw (weight transpose) + ONE persistent kernel (256 x 1024, 1/CU).
// R6: G-phases re-tiled: block = 4 batches x 64 gate-rows (8 bg x 32 rg). h-state staged in ONE
// LLC round trip (30 KB/block/step vs 190). Weights read from transposed WT[k][c] (c pre-permuted
// so a wave reads 64 consecutive floats); blocks sharing a weight slice sit on one XCD (blk%8).
// Gate partials reduced via LDS atomicAdd (ds_add_f32). kslice/va on-chip pinning kept from R5.
// Cross-block mutable state via relaxed AGENT-scope atomics; barrier = spread-counter relaxed spin.

struct BarCtr { unsigned v; unsigned pad[31]; };  // 128 B apart

struct P {
  const float* listener; const int* outlen; const int* ptgt;
  const float* embed;
  const float *W_ih1, *W_hh1, *b_ih1, *b_hh1;
  const float *W_ih2, *W_hh2, *b_ih2, *b_hh2;
  const float *W_s, *b_s, *W_h, *b_h, *W_v, *b_v, *W_c, *b_c;
  const float *h1_0, *c1_0, *h2_0, *c2_0;
  float* keyT;            // [32][128][2048]
  float* value;           // [32][2048][128]
  float* WT1;             // [896][2048]  transposed+permuted [emb|ctx|h1] weights for gates1
  float* WT2;             // [1024][2048] transposed+permuted [h1|h2] weights for gates2
  float* h1;              // [2][32][512] (cross-block -> atomics)
  float* c1;              // [2][32][512] block-private (plain)
  float* h2;              // [2][32][512] cross-block -> atomics
  float* c2;              // [2][32][512] block-private (plain)
  float* wbuf;            // [32][2048]  cross-block -> atomics
  float* ctxnum;          // [2][32][128] cross-block -> atomics
  float* Ssum;            // [2][32]      cross-block -> atomics
  BarCtr* bar;            // 8 counters
  float* out;
};

__device__ __forceinline__ float sigf(float x) { return 1.0f / (1.0f + expf(-x)); }

__device__ __forceinline__ float gload(const float* p) {
  return __hip_atomic_load(p, __ATOMIC_RELAXED, __HIP_MEMORY_SCOPE_AGENT);
}
__device__ __forceinline__ void gstore(float* p, float v) {
  __hip_atomic_store(p, v, __ATOMIC_RELAXED, __HIP_MEMORY_SCOPE_AGENT);
}
__device__ __forceinline__ void gadd(float* p, float v) {
  __hip_atomic_fetch_add(p, v, __ATOMIC_RELAXED, __HIP_MEMORY_SCOPE_AGENT);
}

// exact jax threefry2x32 (20 rounds)
__device__ __forceinline__ void tf2x32(uint32_t k0, uint32_t k1,
                                       uint32_t x0, uint32_t x1,
                                       uint32_t& o0, uint32_t& o1) {
  uint32_t k2 = k0 ^ k1 ^ 0x1BD11BDAu;
#define TFR(r) { x0 += x1; x1 = (x1 << (r)) | (x1 >> (32 - (r))); x1 ^= x0; }
  x0 += k0; x1 += k1;
  TFR(13) TFR(15) TFR(26) TFR(6)   x0 += k1; x1 += k2 + 1u;
  TFR(17) TFR(29) TFR(16) TFR(24)  x0 += k2; x1 += k0 + 2u;
  TFR(13) TFR(15) TFR(26) TFR(6)   x0 += k0; x1 += k1 + 3u;
  TFR(17) TFR(29) TFR(16) TFR(24)  x0 += k1; x1 += k2 + 4u;
  TFR(13) TFR(15) TFR(26) TFR(6)   x0 += k2; x1 += k0 + 5u;
#undef TFR
  o0 = x0; o1 = x1;
}

__device__ __forceinline__ float gumbel_f(uint32_t bits) {
  float f = __uint_as_float((bits >> 9) | 0x3f800000u) - 1.0f;
  float u = (f == 0.0f) ? 1.17549435e-38f : f;
  return -logf(-logf(u));
}

// ---- software grid barrier: spread counters, relaxed spin, no cache maintenance ----
__device__ __forceinline__ void gbar(BarCtr* bar, int blk, unsigned round) {
  __syncthreads();
  if (threadIdx.x == 0) {
    __hip_atomic_fetch_add(&bar[blk & 7].v, 1u, __ATOMIC_RELAXED, __HIP_MEMORY_SCOPE_AGENT);
    const unsigned tgt = round * 256u;
    for (;;) {
      unsigned s = 0;
#pragma unroll
      for (int c = 0; c < 8; ++c)
        s += __hip_atomic_load(&bar[c].v, __ATOMIC_RELAXED, __HIP_MEMORY_SCOPE_AGENT);
      if (s >= tgt) break;
      __builtin_amdgcn_s_sleep(1);
    }
    asm volatile("" ::: "memory");
  }
  __syncthreads();
}

// ---------------- init ----------------
__global__ void __launch_bounds__(256) k_init(P p) {
  int idx = blockIdx.x * 256 + threadIdx.x;   // grid 64*256 = 16384
  p.h1[idx] = p.h1_0[idx];
  p.c1[idx] = p.c1_0[idx];
  p.h2[idx] = p.h2_0[idx];
  p.c2[idx] = p.c2_0[idx];
  if (idx < 8192) p.ctxnum[idx] = 0.0f;
  if (idx < 64)   p.Ssum[idx]   = 0.0f;
  if (idx < 8)    p.bar[idx].v  = 0u;
}

// ---------------- hoisted projections: key_enc (transposed) + value ----------------
__global__ void __launch_bounds__(256) k_proj(P p) {
  const int blk = blockIdx.x, tid = threadIdx.x;      // grid 4096
  const int b = blk >> 7, tb = blk & 127, t0 = tb * 16;
  __shared__ float lst[16 * 512];                     // 32 KB
  const float* src = p.listener + ((size_t)b * 2048 + t0) * 512;
  for (int n = 0; n < 32; ++n) {
    int idx = n * 256 + tid;
    lst[idx] = src[idx];
  }
  __syncthreads();
  const int c = tid;
  const float* wr = (c < 128) ? (p.W_h + c * 512) : (p.W_v + (c - 128) * 512);
  const float bias = (c < 128) ? p.b_h[c] : p.b_v[c - 128];
  float acc[16];
#pragma unroll
  for (int r = 0; r < 16; ++r) acc[r] = 0.0f;
  for (int k4 = 0; k4 < 128; ++k4) {
    float4 w4 = ((const float4*)wr)[k4];
#pragma unroll
    for (int r = 0; r < 16; ++r) {
      float4 x4 = ((const float4*)(lst + r * 512))[k4];
      acc[r] = fmaf(w4.x, x4.x, fmaf(w4.y, x4.y, fmaf(w4.z, x4.z, fmaf(w4.w, x4.w, acc[r]))));
    }
  }
  if (c < 128) {
#pragma unroll
    for (int r = 0; r < 16; ++r)
      p.keyT[((size_t)b * 128 + c) * 2048 + t0 + r] = acc[r] + bias;
  } else {
#pragma unroll
    for (int r = 0; r < 16; ++r)
      p.value[((size_t)b * 2048 + t0 + r) * 128 + (c - 128)] = acc[r] + bias;
  }
}

// ---------------- weight transpose: WT[k][c], c = rg*64 + gate*16 + jl ----------------
// grow = gate*512 + rg*16 + jl ; WT2 k<512 -> W_ih2[grow][k], else W_hh2[grow][k-512]
//                                WT1 k<384 -> W_ih1[grow][k], else W_hh1[grow][k-384]
__global__ void __launch_bounds__(256) k_tw(P p) {   // grid 960: 512 (WT2 16x32) + 448 (WT1 14x32)
  __shared__ float t[64 * 65];
  const int blk = blockIdx.x, tid = threadIdx.x;
  const float *Wa, *Wb; float* dst; int kt, ct, ka, sA, sB;
  if (blk < 512) { kt = blk >> 5; ct = blk & 31; Wa = p.W_ih2; sA = 512; Wb = p.W_hh2; sB = 512; ka = 512; dst = p.WT2; }
  else { int b2 = blk - 512; kt = b2 >> 5; ct = b2 & 31; Wa = p.W_ih1; sA = 384; Wb = p.W_hh1; sB = 512; ka = 384; dst = p.WT1; }
  for (int n = 0; n < 4; ++n) {
    int fid = n * 256 + tid;                 // 0..1023
    int cl = fid >> 4, k4 = (fid & 15) * 4;
    int grow = ((cl >> 4) * 512) + ct * 16 + (cl & 15);
    int k = kt * 64 + k4;
    float4 v = (k < ka) ? *(const float4*)&Wa[(size_t)grow * sA + k]
                        : *(const float4*)&Wb[(size_t)grow * sB + (k - ka)];
    t[cl * 65 + k4 + 0] = v.x; t[cl * 65 + k4 + 1] = v.y;
    t[cl * 65 + k4 + 2] = v.z; t[cl * 65 + k4 + 3] = v.w;
  }
  __syncthreads();
  for (int n = 0; n < 4; ++n) {
    int fid = n * 256 + tid;
    int kl = fid >> 4, c4 = (fid & 15) * 4;
    int k = kt * 64 + kl;
    float4 o;
    o.x = t[(c4 + 0) * 65 + kl]; o.y = t[(c4 + 1) * 65 + kl];
    o.z = t[(c4 + 2) * 65 + kl]; o.w = t[(c4 + 3) * 65 + kl];
    *(float4*)&dst[(size_t)k * 2048 + ct * 64 + c4] = o;
  }
}

// ---------------- finalize step `step` for batch b: logits + categorical sample ----------------
__device__ void do_finalize(const P& p, int step, int b, int tid, float* sf) {
  const int c = tid;
  const int par = step & 1;
  const float* h2p  = p.h2 + par * 16384 + b * 512;
  const float* ctxp = p.ctxnum + par * 4096 + b * 128;
  const float invS = 1.0f / fmaxf(gload(&p.Ssum[par * 32 + b]), 1e-12f);
#pragma unroll
  for (int n = 0; n < 10; ++n) {
    int idx = n * 64 + c;
    float v = (idx < 512) ? gload(&h2p[idx]) : gload(&ctxp[idx - 512]) * invS;
    sf[idx] = v;
  }
  asm volatile("s_waitcnt vmcnt(0) lgkmcnt(0)" ::: "memory");
  __builtin_amdgcn_wave_barrier();
  const float* wr = p.W_c + c * 640;
  float a0 = 0.f, a1 = 0.f, a2 = 0.f, a3 = 0.f;
#pragma unroll 8
  for (int k4 = 0; k4 < 160; ++k4) {
    float4 w4 = ((const float4*)wr)[k4];
    float4 x4 = ((const float4*)sf)[k4];
    a0 = fmaf(w4.x, x4.x, a0); a1 = fmaf(w4.y, x4.y, a1);
    a2 = fmaf(w4.z, x4.z, a2); a3 = fmaf(w4.w, x4.w, a3);
  }
  float lg = p.b_c[c] + ((a0 + a1) + (a2 + a3));
  p.out[(size_t)(step * 32 + b) * 64 + c] = lg;
  uint32_t n0, n1, r0, r1;
  tf2x32(0u, 2u, 0u, (uint32_t)step, n0, n1);
  tf2x32(n0, n1, 0u, (uint32_t)(b * 64 + c), r0, r1);
  float z = gumbel_f(r0 ^ r1) + lg;
  int ix = c;
  for (int off = 32; off; off >>= 1) {
    float zz = __shfl_xor(z, off, 64); int ii = __shfl_xor(ix, off, 64);
    if (zz > z || (zz == z && ii < ix)) { z = zz; ix = ii; }
  }
  if (c == 0) p.out[131072 + b * 64 + step] = (float)ix;
}

// ---------------- phase G1: block = 4 batches (bg) x 64 gate-rows (rg) ----------------
__device__ void phase_g1(const P& p, int i, float* xT, float* sg, float* sfin, int blk, int tid) {
  const int par = i & 1, q1 = par ^ 1;
  const int bg = blk >> 5, rg = blk & 31;
  if (tid < 256) {   // atts output for step i-1
    int flat = blk * 256 + tid;
    int b = flat >> 11, t = flat & 2047;
    float s = fmaxf(gload(&p.Ssum[q1 * 32 + b]), 1e-12f);
    p.out[133120 + (size_t)((i - 1) * 32 + b) * 2048 + t] = gload(&p.wbuf[b * 2048 + t]) / s;
  }
  {  // stage xT[k][b4] = [emb(256)|ctx(128)|h1(512)], one LLC round trip
    int b4 = tid & 3, kb = (tid >> 2) << 2;
    if (kb < 896) {
      int b = bg * 4 + b4;
      float v0, v1, v2, v3;
      if (kb < 256) {
        int tok = p.ptgt[b * 65 + (i - 1)];       // teacher forcing == 1 always
        const float* e = p.embed + tok * 256 + kb;
        v0 = e[0]; v1 = e[1]; v2 = e[2]; v3 = e[3];
      } else if (kb < 384) {
        float invS = 1.0f / fmaxf(gload(&p.Ssum[q1 * 32 + b]), 1e-12f);
        const float* cx = p.ctxnum + q1 * 4096 + b * 128 + (kb - 256);
        v0 = gload(cx + 0) * invS; v1 = gload(cx + 1) * invS;
        v2 = gload(cx + 2) * invS; v3 = gload(cx + 3) * invS;
      } else {
        const float* h = p.h1 + q1 * 16384 + b * 512 + (kb - 384);
        v0 = gload(h + 0); v1 = gload(h + 1); v2 = gload(h + 2); v3 = gload(h + 3);
      }
      xT[(kb + 0) * 4 + b4] = v0; xT[(kb + 1) * 4 + b4] = v1;
      xT[(kb + 2) * 4 + b4] = v2; xT[(kb + 3) * 4 + b4] = v3;
    }
  }
  if (tid < 256) {   // bias init (same bias for all 4 b)
    int lr = tid & 63;
    int grow = (lr >> 4) * 512 + rg * 16 + (lr & 15);
    sg[tid] = p.b_ih1[grow] + p.b_hh1[grow];
  }
  __syncthreads();
  {  // wave w: K-slice [w*56, w*56+56); lane = gate-row; coalesced WT1 reads + LDS x broadcast
    int w = tid >> 6, lane = tid & 63;
    const float* wp = p.WT1 + (size_t)(w * 56) * 2048 + rg * 64 + lane;
    const float4* xp = (const float4*)(xT + (w * 56) * 4);
    float a0 = 0.f, a1 = 0.f, a2 = 0.f, a3 = 0.f;
#pragma unroll 8
    for (int k = 0; k < 56; ++k) {
      float wv = wp[(size_t)k * 2048];
      float4 x4 = xp[k];
      a0 = fmaf(wv, x4.x, a0); a1 = fmaf(wv, x4.y, a1);
      a2 = fmaf(wv, x4.z, a2); a3 = fmaf(wv, x4.w, a3);
    }
    atomicAdd(&sg[lane], a0);        atomicAdd(&sg[64 + lane], a1);
    atomicAdd(&sg[128 + lane], a2);  atomicAdd(&sg[192 + lane], a3);
  }
  __syncthreads();
  if (tid < 64) {   // act1: 4 b x 16 j
    int bb = tid >> 4, jl = tid & 15;
    int b = bg * 4 + bb, j = rg * 16 + jl;
    float gi = sg[bb * 64 + jl];
    float gf = sg[bb * 64 + 16 + jl];
    float gg = sg[bb * 64 + 32 + jl];
    float go = sg[bb * 64 + 48 + jl];
    float cp = p.c1[q1 * 16384 + b * 512 + j];
    float c  = sigf(gf) * cp + sigf(gi) * tanhf(gg);
    gstore(&p.h1[par * 16384 + b * 512 + j], sigf(go) * tanhf(c));
    p.c1[par * 16384 + b * 512 + j] = c;
  }
  if (blk < 32 && tid < 64) do_finalize(p, i - 1, blk, tid, sfin);
}

// ---------------- phase G2: same tiling, K = 1024 = [h1|h2prev] ----------------
__device__ void phase_g2(const P& p, int i, float* xT, float* sg, int blk, int tid) {
  const int par = i & 1, q1 = par ^ 1;
  const int bg = blk >> 5, rg = blk & 31;
  if (blk < 4) gstore(&p.ctxnum[q1 * 4096 + blk * 1024 + tid], 0.0f);
  if (blk == 4 && tid < 32) gstore(&p.Ssum[q1 * 32 + tid], 0.0f);
  {  // stage xT[k][b4], one LLC round trip
    int b4 = tid & 3, kb = (tid >> 2) << 2;
    int b = bg * 4 + b4;
    const float* h = (kb < 512) ? (p.h1 + par * 16384 + b * 512 + kb)
                                : (p.h2 + q1 * 16384 + b * 512 + (kb - 512));
    float v0 = gload(h + 0), v1 = gload(h + 1), v2 = gload(h + 2), v3 = gload(h + 3);
    xT[(kb + 0) * 4 + b4] = v0; xT[(kb + 1) * 4 + b4] = v1;
    xT[(kb + 2) * 4 + b4] = v2; xT[(kb + 3) * 4 + b4] = v3;
  }
  if (tid < 256) {
    int lr = tid & 63;
    int grow = (lr >> 4) * 512 + rg * 16 + (lr & 15);
    sg[tid] = p.b_ih2[grow] + p.b_hh2[grow];
  }
  __syncthreads();
  {
    int w = tid >> 6, lane = tid & 63;
    const float* wp = p.WT2 + (size_t)(w * 64) * 2048 + rg * 64 + lane;
    const float4* xp = (const float4*)(xT + (w * 64) * 4);
    float a0 = 0.f, a1 = 0.f, a2 = 0.f, a3 = 0.f;
#pragma unroll 8
    for (int k = 0; k < 64; ++k) {
      float wv = wp[(size_t)k * 2048];
      float4 x4 = xp[k];
      a0 = fmaf(wv, x4.x, a0); a1 = fmaf(wv, x4.y, a1);
      a2 = fmaf(wv, x4.z, a2); a3 = fmaf(wv, x4.w, a3);
    }
    atomicAdd(&sg[lane], a0);        atomicAdd(&sg[64 + lane], a1);
    atomicAdd(&sg[128 + lane], a2);  atomicAdd(&sg[192 + lane], a3);
  }
  __syncthreads();
  if (tid < 64) {   // act2
    int bb = tid >> 4, jl = tid & 15;
    int b = bg * 4 + bb, j = rg * 16 + jl;
    float gi = sg[bb * 64 + jl];
    float gf = sg[bb * 64 + 16 + jl];
    float gg = sg[bb * 64 + 32 + jl];
    float go = sg[bb * 64 + 48 + jl];
    float cp = p.c2[q1 * 16384 + b * 512 + j];
    float c  = sigf(gf) * cp + sigf(gi) * tanhf(gg);
    gstore(&p.h2[par * 16384 + b * 512 + j], sigf(go) * tanhf(c));
    p.c2[par * 16384 + b * 512 + j] = c;
  }
}

// ---------------- phase ATT: query, energies (LDS keys), ctx (value in regs) ----------------
__device__ __forceinline__ void phase_att(const P& p, int i, float* smem, const float* kslice,
                                          const float va[32], int blk, int tid) {
  const int par = i & 1;
  const int b = blk >> 3;
  float* sh2 = smem;          // 512
  float* sq  = smem + 512;    // 128
  float* sqp = smem + 640;    // 512
  float* se  = smem + 1152;   // 1024
  float* sw  = smem + 2176;   // 256
  float* swr = smem + 2432;   // 8
  float* sc  = smem + 2440;   // 1024  (ends 3464 < 4096)
  const float* h2p = p.h2 + par * 16384 + b * 512;
  if (tid < 512) sh2[tid] = gload(&h2p[tid]);
  __syncthreads();
  if (tid < 512) {
    int col = tid & 127, qh = tid >> 7;
    const float* wr = p.W_s + col * 512 + qh * 128;
    const float4* h4p = (const float4*)(sh2 + qh * 128);
    float a0 = 0.f, a1 = 0.f, a2 = 0.f, a3 = 0.f;
#pragma unroll
    for (int j4 = 0; j4 < 32; ++j4) {
      float4 w4 = ((const float4*)wr)[j4], h4 = h4p[j4];
      a0 = fmaf(w4.x, h4.x, a0); a1 = fmaf(w4.y, h4.y, a1);
      a2 = fmaf(w4.z, h4.z, a2); a3 = fmaf(w4.w, h4.w, a3);
    }
    sqp[qh * 128 + col] = (a0 + a1) + (a2 + a3);
  }
  __syncthreads();
  if (tid < 128) sq[tid] = p.b_s[tid] + sqp[tid] + sqp[128 + tid] + sqp[256 + tid] + sqp[384 + tid];
  __syncthreads();
  {
    int tt = tid & 255, kq = tid >> 8;
    const float* kc = kslice + tt;
    const int kb = kq * 32;
    float e0 = 0.f, e1 = 0.f, e2 = 0.f, e3 = 0.f;
#pragma unroll 8
    for (int k = 0; k < 32; k += 4) {
      e0 = fmaf(kc[(kb + k + 0) * 256], sq[kb + k + 0], e0);
      e1 = fmaf(kc[(kb + k + 1) * 256], sq[kb + k + 1], e1);
      e2 = fmaf(kc[(kb + k + 2) * 256], sq[kb + k + 2], e2);
      e3 = fmaf(kc[(kb + k + 3) * 256], sq[kb + k + 3], e3);
    }
    se[kq * 256 + tt] = (e0 + e1) + (e2 + e3);
  }
  __syncthreads();
  if (tid < 256) {
    const int ch = blk & 7, t0 = ch * 256;
    int t = t0 + tid;
    float e = se[tid] + se[256 + tid] + se[512 + tid] + se[768 + tid];
    const int len = p.outlen[b];
    bool msk = (b == 0) || (t < len);
    float wv = msk ? expf(e) : 0.0f;
    gstore(&p.wbuf[b * 2048 + t], wv);
    sw[tid] = wv;
    float s = wv;
    for (int off = 32; off; off >>= 1) s += __shfl_xor(s, off, 64);
    if ((tid & 63) == 0) swr[tid >> 6] = s;
  }
  __syncthreads();
  if (tid == 0) gadd(&p.Ssum[par * 32 + b], swr[0] + swr[1] + swr[2] + swr[3]);
  {
    int v = tid & 127, tp = tid >> 7;
    float c0 = 0.f, c1v = 0.f;
#pragma unroll
    for (int tt2 = 0; tt2 < 32; tt2 += 2) {
      c0  = fmaf(sw[tp * 32 + tt2],     va[tt2],     c0);
      c1v = fmaf(sw[tp * 32 + tt2 + 1], va[tt2 + 1], c1v);
    }
    sc[tp * 128 + v] = c0 + c1v;
  }
  __syncthreads();
  if (tid < 128) {
    float s = 0.f;
#pragma unroll
    for (int tp = 0; tp < 8; ++tp) s += sc[tp * 128 + tid];
    gadd(&p.ctxnum[par * 4096 + b * 128 + tid], s);
  }
}

// ---------------- the persistent decode loop ----------------
__global__ void __launch_bounds__(1024, 4) k_loop(P p) {
  __shared__ __align__(16) float kslice[128 * 256];   // 128 KB key slice
  __shared__ __align__(16) float work[4096 + 256 + 640];  // xT/ATT(16K) + sg(1K) + sfin(2.5K)
  float* xT   = work;
  float* sg   = work + 4096;
  float* sfin = work + 4352;
  const int blk = blockIdx.x, tid = threadIdx.x;
  const int b_att = blk >> 3, ch = blk & 7, t0 = ch * 256;
  {  // one-time pinning of this block's step-invariant attention slice
    const float* ksrc = p.keyT + (size_t)b_att * 262144 + t0;
    for (int n = 0; n < 32; ++n) {
      int idx = n * 1024 + tid;
      int k = idx >> 8, tt = idx & 255;
      kslice[k * 256 + tt] = ksrc[(size_t)k * 2048 + tt];
    }
  }
  float va[32];
  {
    int v = tid & 127, tp = tid >> 7;
    const float* vb = p.value + ((size_t)(b_att * 2048 + t0 + tp * 32)) * 128 + v;
#pragma unroll
    for (int tt2 = 0; tt2 < 32; ++tt2) va[tt2] = vb[(size_t)tt2 * 128];
  }
  __syncthreads();
  unsigned nb = 0;
  phase_att(p, 0, work, kslice, va, blk, tid);
  for (int i = 1; i < 64; ++i) {
    gbar(p.bar, blk, ++nb);
    phase_g1(p, i, xT, sg, sfin, blk, tid);
    gbar(p.bar, blk, ++nb);
    phase_g2(p, i, xT, sg, blk, tid);
    gbar(p.bar, blk, ++nb);
    phase_att(p, i, work, kslice, va, blk, tid);
  }
  gbar(p.bar, blk, ++nb);
  if (tid < 256) {   // FIN: atts(63)
    int flat = blk * 256 + tid;
    int b = flat >> 11, t = flat & 2047;
    float s = fmaxf(gload(&p.Ssum[1 * 32 + b]), 1e-12f);
    p.out[133120 + (size_t)(63 * 32 + b) * 2048 + t] = gload(&p.wbuf[b * 2048 + t]) / s;
  }
  if (blk < 32 && tid < 64) do_finalize(p, 63, blk, tid, sfin);
}

extern "C" void kernel_launch(void* const* d_in, const int* in_sizes, int n_in,
                              void* d_out, int out_size, void* d_ws, size_t ws_size,
                              hipStream_t stream) {
  P p;
  p.listener = (const float*)d_in[0];
  p.outlen   = (const int*)d_in[1];
  p.ptgt     = (const int*)d_in[2];
  // d_in[3] = teacher_forcing (==1: always teacher-forced)
  p.embed = (const float*)d_in[4];
  p.W_ih1 = (const float*)d_in[5];  p.W_hh1 = (const float*)d_in[6];
  p.b_ih1 = (const float*)d_in[7];  p.b_hh1 = (const float*)d_in[8];
  p.W_ih2 = (const float*)d_in[9];  p.W_hh2 = (const float*)d_in[10];
  p.b_ih2 = (const float*)d_in[11]; p.b_hh2 = (const float*)d_in[12];
  p.W_s = (const float*)d_in[13]; p.b_s = (const float*)d_in[14];
  p.W_h = (const float*)d_in[15]; p.b_h = (const float*)d_in[16];
  p.W_v = (const float*)d_in[17]; p.b_v = (const float*)d_in[18];
  p.W_c = (const float*)d_in[19]; p.b_c = (const float*)d_in[20];
  p.h1_0 = (const float*)d_in[21]; p.c1_0 = (const float*)d_in[22];
  p.h2_0 = (const float*)d_in[23]; p.c2_0 = (const float*)d_in[24];

  char* w = (char*)d_ws;
  p.keyT   = (float*)w; w += (size_t)32 * 128 * 2048 * 4;   // 32 MB
  p.value  = (float*)w; w += (size_t)32 * 2048 * 128 * 4;   // 32 MB
  p.WT1    = (float*)w; w += (size_t)896 * 2048 * 4;        // 7 MB
  p.WT2    = (float*)w; w += (size_t)1024 * 2048 * 4;       // 8 MB
  p.h1  = (float*)w; w += 2 * 32 * 512 * 4;
  p.c1  = (float*)w; w += 2 * 32 * 512 * 4;
  p.h2  = (float*)w; w += 2 * 32 * 512 * 4;
  p.c2  = (float*)w; w += 2 * 32 * 512 * 4;
  p.wbuf   = (float*)w; w += 32 * 2048 * 4;
  p.ctxnum = (float*)w; w += 2 * 32 * 128 * 4;
  p.Ssum   = (float*)w; w += 2 * 32 * 4;
  p.bar    = (BarCtr*)w; w += 8 * sizeof(BarCtr);
  p.out = (float*)d_out;

  k_init<<<64, 256, 0, stream>>>(p);
  k_proj<<<4096, 256, 0, stream>>>(p);
  k_tw<<<960, 256, 0, stream>>>(p);
  k_loop<<<256, 1024, 0, stream>>>(p);
}